// Round 4
// baseline (7420.727 us; speedup 1.0000x reference)
//
#include <hip/hip_runtime.h>

#define T_LEN 4096
#define E_DIM 1024
#define H_DIM 512
#define NT_DIM 32
#define NG 3072          // 2 * 3H columns of gi

typedef __attribute__((ext_vector_type(8))) short bf16x8;
typedef __attribute__((ext_vector_type(4))) float f32x4;
typedef __attribute__((ext_vector_type(4))) unsigned int u32x4;
typedef unsigned long long ull;

__device__ inline unsigned short f2bf(float f) {
    unsigned int u = __float_as_uint(f);
    unsigned int r = (u + 0x7fffu + ((u >> 16) & 1u)) >> 16;
    return (unsigned short)r;
}
__device__ inline float bf2f(unsigned short u) {
    return __uint_as_float(((unsigned int)u) << 16);
}
__device__ inline ull packhs(float v, unsigned tag) {
    return (ull)__float_as_uint(v) | ((ull)tag << 32);
}

// ---------- kernel 1: embedding gather + bf16 cast  (xb[t][e]) ----------
__global__ void embed_cast(const int* __restrict__ sent, const float* __restrict__ emb,
                           unsigned short* __restrict__ xb) {
    int t = blockIdx.x;
    int row = sent[t];
    const float4* src = (const float4*)(emb + (size_t)row * E_DIM);
    ushort4* dst = (ushort4*)(xb + (size_t)t * E_DIM);
    float4 v = src[threadIdx.x];
    ushort4 o;
    o.x = f2bf(v.x); o.y = f2bf(v.y); o.z = f2bf(v.z); o.w = f2bf(v.w);
    dst[threadIdx.x] = o;
}

// ---------- kernel 2: W_ih (f then b) -> bf16, concat rows ----------
__global__ void wcast(const float* __restrict__ wf, const float* __restrict__ wb_,
                      unsigned short* __restrict__ w) {
    int r = blockIdx.x;  // 0..3071
    const float* src = (r < 1536) ? (wf + (size_t)r * E_DIM) : (wb_ + (size_t)(r - 1536) * E_DIM);
    const float4* s4 = (const float4*)src;
    ushort4* dst = (ushort4*)(w + (size_t)r * E_DIM);
    float4 v = s4[threadIdx.x];
    ushort4 o;
    o.x = f2bf(v.x); o.y = f2bf(v.y); o.z = f2bf(v.z); o.w = f2bf(v.w);
    dst[threadIdx.x] = o;
}

// ---------- kernel 3: gi = xb @ wb^T + b_ih   [4096 x 3072] -> bf16 ----------
#define LDST 40
__global__ __launch_bounds__(256) void gi_gemm(const unsigned short* __restrict__ xb,
                                               const unsigned short* __restrict__ wb,
                                               const float* __restrict__ bihf,
                                               const float* __restrict__ bihb,
                                               unsigned short* __restrict__ gi) {
    __shared__ __align__(16) unsigned short As[64 * LDST];
    __shared__ __align__(16) unsigned short Bs[64 * LDST];
    int tile_m = (blockIdx.x % 64) * 64;
    int tile_n = (blockIdx.x / 64) * 64;
    int tid = threadIdx.x;
    int lane = tid & 63, wv = tid >> 6;
    int quad = lane >> 4, r15 = lane & 15;
    int srow = tid >> 2, sseg = tid & 3;

    f32x4 acc[4] = {};
    for (int kb = 0; kb < E_DIM; kb += 32) {
        uint4 a = *(const uint4*)(xb + (size_t)(tile_m + srow) * E_DIM + kb + sseg * 8);
        uint4 b = *(const uint4*)(wb + (size_t)(tile_n + srow) * E_DIM + kb + sseg * 8);
        *(uint4*)&As[srow * LDST + sseg * 8] = a;
        *(uint4*)&Bs[srow * LDST + sseg * 8] = b;
        __syncthreads();
        bf16x8 af = *(bf16x8*)&As[(wv * 16 + r15) * LDST + quad * 8];
#pragma unroll
        for (int nt = 0; nt < 4; nt++) {
            bf16x8 bf = *(bf16x8*)&Bs[(nt * 16 + r15) * LDST + quad * 8];
            acc[nt] = __builtin_amdgcn_mfma_f32_16x16x32_bf16(af, bf, acc[nt], 0, 0, 0);
        }
        __syncthreads();
    }
#pragma unroll
    for (int nt = 0; nt < 4; nt++) {
        int gn = tile_n + nt * 16 + r15;
        float bias = (gn < 1536) ? bihf[gn] : bihb[gn - 1536];
#pragma unroll
        for (int rg = 0; rg < 4; rg++) {
            int gm = tile_m + wv * 16 + quad * 4 + rg;
            gi[(size_t)gm * NG + gn] = f2bf(acc[nt][rg] + bias);
        }
    }
}

// ---------- init: zero the h-exchange planes (slow hx + fast L2 rings) ----------
__global__ __launch_bounds__(256) void init_hx(ull* __restrict__ hxf, ull* __restrict__ hxb,
                                               ull* __restrict__ ff, ull* __restrict__ fb) {
    size_t stride = (size_t)gridDim.x * 256;
    size_t i = (size_t)blockIdx.x * 256 + threadIdx.x;
    for (size_t j = i; j < 2097152; j += stride) { hxf[j] = 0; hxb[j] = 0; }
    if (i < 32768) { ff[i] = 0; fb[i] = 0; }
}

// ---------- kernel 4: persistent bidirectional GRU recurrence ----------
// XCD-local h exchange. Grid = 512 candidate blocks; HW round-robins blocks
// across the 8 XCDs (bid%8). Blocks with bid%8==0 -> fwd (co-located on one
// XCD, sharing one coherent L2); bid%8==1 -> bwd; others exit.
// Producers store h {f32,tag} 8B slots to BOTH:
//   fast: 64-row ring in XCD-local L2 (plain store, sc0 scope)  <- critical path
//   slow: full IF-scope plane (agent atomic)                    <- fallback + out_gemm
// Consumers (wave 0) poll the fast ring with sc0 loads (XCD-L2 hit ~200cy vs
// ~900+ via IF). If the co-location assumption fails, the fast poll times out
// and the WG STICKILY falls back to the proven sc0+sc1 slow poll -> correct
// under ANY block->XCD mapping; the mapping only affects speed.
// Worker: 64 WG/dir x 256 thr (4 waves). Wave w owns cols {g*8+2w, g*8+2w+1}
// (half = l>>5), lane covers 16 k (kq=l&31) -> 48 FMA/lane, reduce via
// shfl_xor 1..16 within 32-lane halves (no cross-wave reduce, no part[]).
// LDS broadcast: h[k] at hsh[(k>>4)*20 + (k&15)] (20-stride: 16B-aligned
// float4 reads, start-banks tile all 32 banks -> <=4-way conflicts).
__global__ __launch_bounds__(256, 2) void gru_rec(
    const float* __restrict__ whhf, const float* __restrict__ bhhf,
    const float* __restrict__ whhb, const float* __restrict__ bhhb,
    const unsigned short* __restrict__ gi,
    ull* __restrict__ hxf, ull* __restrict__ hxb,
    ull* __restrict__ fastf, ull* __restrict__ fastb) {
    int x8 = blockIdx.x & 7;
    if (x8 > 1) return;                    // only the two home-XCD lanes survive
    int dir = x8;
    int g = blockIdx.x >> 3;               // 0..63
    const float* whh = dir ? whhb : whhf;
    const float* bhh = dir ? bhhb : bhhf;
    ull* hx   = dir ? hxb   : hxf;
    ull* fast = dir ? fastb : fastf;

    int t = threadIdx.x;
    int w = t >> 6;                        // wave 0..3
    int l = t & 63;
    int kq = l & 31;                       // k-part: k in [16kq, 16kq+16)
    int half = l >> 5;
    int c = g * 8 + w * 2 + half;          // global output column
    bool owner = (kq == 0);

    // persistent weights: 3 gates x 16 k = 12 float4 = 48 VGPRs
    float4 wr[4], wz[4], wn[4];
    {
        const float* pw = whh + (size_t)c * H_DIM + kq * 16;
#pragma unroll
        for (int j = 0; j < 4; j++) {
            wr[j] = *(const float4*)(pw + j * 4);
            wz[j] = *(const float4*)(pw + 512 * H_DIM + j * 4);
            wn[j] = *(const float4*)(pw + 1024 * H_DIM + j * 4);
        }
    }
    float bias_r = 0.f, bias_z = 0.f, bias_n = 0.f, h_own = 0.f;
    if (owner) { bias_r = bhh[c]; bias_z = bhh[c + 512]; bias_n = bhh[c + 1024]; }

    // padded LDS broadcast: h[k] -> hsh[(k>>4)*20 + (k&15)], 640 floats
    __shared__ __align__(16) float hsh[640];
    for (int i = t; i < 640; i += 256) hsh[i] = 0.f;     // h_{-1} = 0
    __syncthreads();

    bool fast_on = true;   // sticky: falls to slow path permanently on timeout

    for (int s = 0; s < T_LEN; s++) {
        int row = dir ? (T_LEN - 1 - s) : s;
        // gi loads issued first — in flight during the poll/barrier
        float gir = 0.f, giz = 0.f, gin = 0.f;
        if (owner) {
            const unsigned short* gp = gi + (size_t)row * NG + dir * 1536 + c;
            gir = bf2f(gp[0]); giz = bf2f(gp[512]); gin = bf2f(gp[1024]);
        }

        float hv[8];
        if (w == 0 && s > 0) {
            int prow = dir ? (T_LEN - s) : (s - 1);
            unsigned et = (unsigned)s;
            ull fa = (ull)(fast + ((size_t)(prow & 63) * H_DIM + 8 * l));
            ull sa = (ull)(hx + ((size_t)prow * H_DIM + 8 * l));
            u32x4 d0, d1, d2, d3;
            bool got = false;
            if (fast_on) {
                int tries = (s == 1) ? 4096 : 24;
                for (int it = 0; it < tries; ++it) {
                    asm volatile("global_load_dwordx4 %0, %1, off sc0" : "=v"(d0) : "v"(fa));
                    asm volatile("global_load_dwordx4 %0, %1, off offset:16 sc0" : "=v"(d1) : "v"(fa));
                    asm volatile("global_load_dwordx4 %0, %1, off offset:32 sc0" : "=v"(d2) : "v"(fa));
                    asm volatile("global_load_dwordx4 %0, %1, off offset:48 sc0" : "=v"(d3) : "v"(fa));
                    asm volatile("s_waitcnt vmcnt(0)" ::: "memory");
                    __builtin_amdgcn_sched_barrier(0);
                    bool ok = (d0.y == et) & (d0.w == et) & (d1.y == et) & (d1.w == et)
                            & (d2.y == et) & (d2.w == et) & (d3.y == et) & (d3.w == et);
                    if (__all(ok)) { got = true; break; }
                }
                if (!got) fast_on = false;
            }
            if (!got) {
                for (;;) {
                    asm volatile("global_load_dwordx4 %0, %1, off sc0 sc1" : "=v"(d0) : "v"(sa));
                    asm volatile("global_load_dwordx4 %0, %1, off offset:16 sc0 sc1" : "=v"(d1) : "v"(sa));
                    asm volatile("global_load_dwordx4 %0, %1, off offset:32 sc0 sc1" : "=v"(d2) : "v"(sa));
                    asm volatile("global_load_dwordx4 %0, %1, off offset:48 sc0 sc1" : "=v"(d3) : "v"(sa));
                    asm volatile("s_waitcnt vmcnt(0)" ::: "memory");
                    __builtin_amdgcn_sched_barrier(0);
                    bool ok = (d0.y == et) & (d0.w == et) & (d1.y == et) & (d1.w == et)
                            & (d2.y == et) & (d2.w == et) & (d3.y == et) & (d3.w == et);
                    if (__all(ok)) break;
                }
            }
            hv[0] = __uint_as_float(d0.x); hv[1] = __uint_as_float(d0.z);
            hv[2] = __uint_as_float(d1.x); hv[3] = __uint_as_float(d1.z);
            hv[4] = __uint_as_float(d2.x); hv[5] = __uint_as_float(d2.z);
            hv[6] = __uint_as_float(d3.x); hv[7] = __uint_as_float(d3.z);
        }
        __syncthreads();   // barA: all waves done reading previous hsh
        if (w == 0 && s > 0) {
            int base = (l >> 1) * 20 + (l & 1) * 8;    // h[8l..8l+8) packed
            *(float4*)&hsh[base]     = make_float4(hv[0], hv[1], hv[2], hv[3]);
            *(float4*)&hsh[base + 4] = make_float4(hv[4], hv[5], hv[6], hv[7]);
        }
        __syncthreads();   // barB: hsh = h(s-1) ready

        const float* hb = &hsh[kq * 20];
        float4 h0 = *(const float4*)(hb);
        float4 h1 = *(const float4*)(hb + 4);
        float4 h2 = *(const float4*)(hb + 8);
        float4 h3 = *(const float4*)(hb + 12);
        float pr, pz, pn;
        pr  = wr[0].x * h0.x + wr[0].y * h0.y + wr[0].z * h0.z + wr[0].w * h0.w
            + wr[1].x * h1.x + wr[1].y * h1.y + wr[1].z * h1.z + wr[1].w * h1.w
            + wr[2].x * h2.x + wr[2].y * h2.y + wr[2].z * h2.z + wr[2].w * h2.w
            + wr[3].x * h3.x + wr[3].y * h3.y + wr[3].z * h3.z + wr[3].w * h3.w;
        pz  = wz[0].x * h0.x + wz[0].y * h0.y + wz[0].z * h0.z + wz[0].w * h0.w
            + wz[1].x * h1.x + wz[1].y * h1.y + wz[1].z * h1.z + wz[1].w * h1.w
            + wz[2].x * h2.x + wz[2].y * h2.y + wz[2].z * h2.z + wz[2].w * h2.w
            + wz[3].x * h3.x + wz[3].y * h3.y + wz[3].z * h3.z + wz[3].w * h3.w;
        pn  = wn[0].x * h0.x + wn[0].y * h0.y + wn[0].z * h0.z + wn[0].w * h0.w
            + wn[1].x * h1.x + wn[1].y * h1.y + wn[1].z * h1.z + wn[1].w * h1.w
            + wn[2].x * h2.x + wn[2].y * h2.y + wn[2].z * h2.z + wn[2].w * h2.w
            + wn[3].x * h3.x + wn[3].y * h3.y + wn[3].z * h3.z + wn[3].w * h3.w;
        // reduce over kq (lane bits 0..4): stays within each 32-lane half
        pr += __shfl_xor(pr, 1);  pz += __shfl_xor(pz, 1);  pn += __shfl_xor(pn, 1);
        pr += __shfl_xor(pr, 2);  pz += __shfl_xor(pz, 2);  pn += __shfl_xor(pn, 2);
        pr += __shfl_xor(pr, 4);  pz += __shfl_xor(pz, 4);  pn += __shfl_xor(pn, 4);
        pr += __shfl_xor(pr, 8);  pz += __shfl_xor(pz, 8);  pn += __shfl_xor(pn, 8);
        pr += __shfl_xor(pr, 16); pz += __shfl_xor(pz, 16); pn += __shfl_xor(pn, 16);

        if (owner) {
            float rr = 1.f / (1.f + __expf(-(gir + pr + bias_r)));
            float zz = 1.f / (1.f + __expf(-(giz + pz + bias_z)));
            float a = gin + rr * (pn + bias_n);
            a = fminf(20.f, fmaxf(-20.f, a));
            float e = __expf(-2.f * a);
            float nn = (1.f - e) / (1.f + e);
            float hnew = (1.f - zz) * nn + zz * h_own;
            h_own = hnew;
            ull pv = packhs(hnew, (unsigned)(s + 1));
            // fast store first (critical path: XCD-local L2), then IF-scope
            ull faddr = (ull)(fast + ((size_t)(row & 63) * H_DIM + c));
            asm volatile("global_store_dwordx2 %0, %1, off sc0" :: "v"(faddr), "v"(pv) : "memory");
            __hip_atomic_store(hx + (size_t)row * H_DIM + c, pv,
                               __ATOMIC_RELAXED, __HIP_MEMORY_SCOPE_AGENT);
        }
    }
}

// ---------- kernel 5: out = [hf|hb] @ W_out^T   [4096 x 32] ----------
__global__ __launch_bounds__(256) void out_gemm(const ull* __restrict__ hxf,
                                                const ull* __restrict__ hxb,
                                                const float* __restrict__ wout,
                                                float* __restrict__ out) {
    __shared__ __align__(16) float ls[8][1028];
    int t0 = blockIdx.x * 8;
    int tid = threadIdx.x;
#pragma unroll
    for (int i = 0; i < 8; i++) {
        int col = tid * 4;   // 0..1020
        const ull* src = (col < 512) ? (hxf + (size_t)(t0 + i) * H_DIM + col)
                                     : (hxb + (size_t)(t0 + i) * H_DIM + (col - 512));
        ull s0 = src[0], s1 = src[1], s2 = src[2], s3 = src[3];
        ls[i][col + 0] = __uint_as_float((unsigned)s0);
        ls[i][col + 1] = __uint_as_float((unsigned)s1);
        ls[i][col + 2] = __uint_as_float((unsigned)s2);
        ls[i][col + 3] = __uint_as_float((unsigned)s3);
    }
    __syncthreads();
    int r8 = tid >> 5, gg = tid & 31;
    const float4* wp = (const float4*)(wout + (size_t)gg * 1024);
    float sum = 0.f;
#pragma unroll 8
    for (int j = 0; j < 256; j++) {
        float4 w = wp[j];
        float4 h = *(const float4*)&ls[r8][j * 4];
        sum += w.x * h.x + w.y * h.y + w.z * h.z + w.w * h.w;
    }
    out[(size_t)(t0 + r8) * NT_DIM + gg] = sum;
}

extern "C" void kernel_launch(void* const* d_in, const int* in_sizes, int n_in,
                              void* d_out, int out_size, void* d_ws, size_t ws_size,
                              hipStream_t stream) {
    const int*   sent = (const int*)d_in[0];
    const float* emb  = (const float*)d_in[1];
    const float* wihf = (const float*)d_in[2];
    const float* whhf = (const float*)d_in[3];
    const float* bihf = (const float*)d_in[4];
    const float* bhhf = (const float*)d_in[5];
    const float* wihb = (const float*)d_in[6];
    const float* whhb = (const float*)d_in[7];
    const float* bihb = (const float*)d_in[8];
    const float* bhhb = (const float*)d_in[9];
    const float* wout = (const float*)d_in[10];

    char* ws = (char*)d_ws;
    unsigned short* gi  = (unsigned short*)(ws);              // 4096*3072*2 = 25165824
    unsigned short* xb  = (unsigned short*)(ws + 25165824);   // 4096*1024*2 =  8388608
    unsigned short* wb  = (unsigned short*)(ws + 33554432);   // 3072*1024*2 =  6291456
    ull*            hxf = (ull*)(ws + 39845888);              // 4096*512*8  = 16777216
    ull*            hxb = (ull*)(ws + 56623104);              // 16777216 (total 73400320)
    // fast L2 rings (64 rows x 512 slots x 8B = 256KB each) reuse the xb/wb
    // regions, which are dead after gi_gemm completes (stream-ordered).
    ull*            fastf = (ull*)(ws + 25165824);
    ull*            fastb = (ull*)(ws + 33554432);
    float*          out = (float*)d_out;

    embed_cast<<<T_LEN, 256, 0, stream>>>(sent, emb, xb);
    wcast<<<NG, 256, 0, stream>>>(wihf, wihb, wb);
    gi_gemm<<<64 * 48, 256, 0, stream>>>(xb, wb, bihf, bihb, gi);
    init_hx<<<2048, 256, 0, stream>>>(hxf, hxb, fastf, fastb);
    gru_rec<<<512, 256, 0, stream>>>(whhf, bhhf, whhb, bhhb, gi, hxf, hxb, fastf, fastb);
    out_gemm<<<T_LEN / 8, 256, 0, stream>>>(hxf, hxb, wout, out);
}